// Round 1
// baseline (2530.940 us; speedup 1.0000x reference)
//
#include <hip/hip_runtime.h>
#include <math.h>

// ---------------- constants ----------------
#define LSEQ  1025
#define BATCH 8
#define TOK   (BATCH*LSEQ)   // 8200
#define DM    128
#define DI    256
#define DS    16
#define DTR   8
#define CHUNK 32
#define NCH   33             // ceil(1025/32)

__device__ __forceinline__ float sigm_(float x){ return 1.f/(1.f+expf(-x)); }
__device__ __forceinline__ float silu_(float x){ return x*sigm_(x); }
__device__ __forceinline__ float gelu_(float x){ return 0.5f*x*(1.f+erff(x*0.70710678118654752440f)); }
__device__ __forceinline__ float softplus_(float x){ return fmaxf(x,0.f) + log1pf(expf(-fabsf(x))); }

// ---------------- patch embed + cls + pos ----------------
__global__ __launch_bounds__(128) void patch_embed(
    const float* __restrict__ img, const float* __restrict__ pw,
    const float* __restrict__ pb, const float* __restrict__ cls,
    const float* __restrict__ pos, float* __restrict__ x)
{
  int bid = blockIdx.x;             // 0..TOK-1
  int b = bid / LSEQ, t = bid - b*LSEQ;
  int c = threadIdx.x;              // 0..127
  if (t == 0) {
    x[(size_t)bid*DM + c] = cls[c] + pos[c];
    return;
  }
  __shared__ float sp[256];
  int p = t - 1, py = p >> 5, px = p & 31;
  const float* ib = img + ((size_t)b*512 + py*16)*512 + px*16;
  int i = c >> 3, j = (c & 7)*2;
  float2 v = *(const float2*)(ib + i*512 + j);
  sp[i*16+j] = v.x; sp[i*16+j+1] = v.y;
  __syncthreads();
  const float* wr = pw + (size_t)c*256;
  float acc = 0.f;
  #pragma unroll 8
  for (int k = 0; k < 256; k += 4) {
    float4 w4 = *(const float4*)(wr + k);
    acc += sp[k]*w4.x + sp[k+1]*w4.y + sp[k+2]*w4.z + sp[k+3]*w4.w;
  }
  x[(size_t)bid*DM + c] = acc + pb[c] + pos[(size_t)t*DM + c];
}

// ---------------- layernorm over 128 ----------------
__global__ __launch_bounds__(64) void ln128(
    const float* __restrict__ in, float* __restrict__ out,
    const float* __restrict__ w, const float* __restrict__ b)
{
  int row = blockIdx.x;
  int lane = threadIdx.x;
  float2 v = *(const float2*)(in + (size_t)row*DM + lane*2);
  float s = v.x + v.y;
  #pragma unroll
  for (int o = 32; o; o >>= 1) s += __shfl_xor(s, o);
  float mean = s * (1.f/DM);
  float dx = v.x - mean, dy = v.y - mean;
  float q = dx*dx + dy*dy;
  #pragma unroll
  for (int o = 32; o; o >>= 1) q += __shfl_xor(q, o);
  float inv = 1.f / sqrtf(q*(1.f/DM) + 1e-5f);
  float2 o2;
  o2.x = dx*inv*w[lane*2]   + b[lane*2];
  o2.y = dy*inv*w[lane*2+1] + b[lane*2+1];
  *(float2*)(out + (size_t)row*DM + lane*2) = o2;
}

// ---------------- generic fp32 GEMM:  C = A @ W^T  (A: MxK, W: NxK) ----------------
// A (and W) may be split at Ksplit between two buffers (row length = segment K).
// EPI: 1 = gelu(acc+bias) -> C[ldc] ; 2 = C[ldc] += acc+bias ; 3 = split store u/z (in_proj)
template<int EPI>
__global__ __launch_bounds__(256) void sgemm(
    const float* __restrict__ A1, const float* __restrict__ A2,
    const float* __restrict__ W1, const float* __restrict__ W2,
    const float* __restrict__ bias, float* __restrict__ C,
    float* __restrict__ C2, int M, int N, int K, int Ksplit, int ldc)
{
  __shared__ float As[16][68];
  __shared__ float Bs[16][68];
  int m0 = blockIdx.x * 64, n0 = blockIdx.y * 64;
  int tid = threadIdx.x;
  int lr = tid >> 2;            // 0..63
  int lk = (tid & 3) * 4;       // 0,4,8,12
  int ty = tid >> 4, tx = tid & 15;
  int K2 = K - Ksplit;
  float acc[4][4] = {};

  for (int kt = 0; kt < K; kt += 16) {
    int k = kt + lk;
    {
      int m = m0 + lr;
      float4 v = make_float4(0.f,0.f,0.f,0.f);
      if (m < M) {
        if (k < Ksplit) v = *(const float4*)(A1 + (size_t)m*Ksplit + k);
        else            v = *(const float4*)(A2 + (size_t)m*K2 + (k - Ksplit));
      }
      As[lk+0][lr]=v.x; As[lk+1][lr]=v.y; As[lk+2][lr]=v.z; As[lk+3][lr]=v.w;
      int n = n0 + lr;
      float4 wv;
      if (k < Ksplit) wv = *(const float4*)(W1 + (size_t)n*Ksplit + k);
      else            wv = *(const float4*)(W2 + (size_t)n*K2 + (k - Ksplit));
      Bs[lk+0][lr]=wv.x; Bs[lk+1][lr]=wv.y; Bs[lk+2][lr]=wv.z; Bs[lk+3][lr]=wv.w;
    }
    __syncthreads();
    #pragma unroll
    for (int kk = 0; kk < 16; kk++) {
      float a[4], bb[4];
      #pragma unroll
      for (int i=0;i<4;i++) a[i] = As[kk][ty*4+i];
      #pragma unroll
      for (int j=0;j<4;j++) bb[j] = Bs[kk][tx*4+j];
      #pragma unroll
      for (int i=0;i<4;i++)
        #pragma unroll
        for (int j=0;j<4;j++) acc[i][j] += a[i]*bb[j];
    }
    __syncthreads();
  }

  int n = n0 + tx*4;
  #pragma unroll
  for (int i=0;i<4;i++) {
    int m = m0 + ty*4 + i;
    if (m >= M) continue;
    float4 r = make_float4(acc[i][0], acc[i][1], acc[i][2], acc[i][3]);
    if (EPI == 3) {
      int dir = n >> 9, rr = n & 511;
      float* dst = (rr < 256) ? (C  + ((size_t)(dir*TOK) + m)*DI + rr)
                              : (C2 + ((size_t)(dir*TOK) + m)*DI + (rr - 256));
      *(float4*)dst = r;
    } else {
      float4 bv = *(const float4*)(bias + n);
      r.x += bv.x; r.y += bv.y; r.z += bv.z; r.w += bv.w;
      float* dst = C + (size_t)m*ldc + n;
      if (EPI == 1) { r.x=gelu_(r.x); r.y=gelu_(r.y); r.z=gelu_(r.z); r.w=gelu_(r.w); }
      if (EPI == 2) { float4 old = *(const float4*)dst; r.x+=old.x; r.y+=old.y; r.z+=old.z; r.w+=old.w; }
      *(float4*)dst = r;
    }
  }
}

// ---------------- causal depthwise conv (dir-aware) + bias + silu ----------------
__global__ __launch_bounds__(256) void conv_silu(
    const float* __restrict__ upre, const float* __restrict__ cw,
    const float* __restrict__ cb, float* __restrict__ u)
{
  int gid = blockIdx.x;            // dir*TOK + m
  int dir = gid / TOK; int m = gid - dir*TOK;
  int b = m / LSEQ, t = m - b*LSEQ;
  int d = threadIdx.x;
  const float* w = cw + ((size_t)dir*DI + d)*4;
  float acc = cb[dir*DI + d];
  #pragma unroll
  for (int k = 0; k < 4; k++) {
    int tt = dir ? (t + 3 - k) : (t - 3 + k);
    if (tt >= 0 && tt < LSEQ)
      acc += upre[((size_t)dir*TOK + (size_t)b*LSEQ + tt)*DI + d] * w[k];
  }
  u[(size_t)gid*DI + d] = silu_(acc);
}

// ---------------- x_proj (40) + dt proj + softplus ; emits dt, B, C ----------------
__global__ __launch_bounds__(64) void xproj(
    const float* __restrict__ u, const float* __restrict__ Wx,
    const float* __restrict__ Wdt, const float* __restrict__ bdt,
    float* __restrict__ dt, float* __restrict__ Bm, float* __restrict__ Cm)
{
  int gid = blockIdx.x;            // dir*TOK + m
  int dir = gid / TOK;
  int lane = threadIdx.x;
  __shared__ float su[256];
  __shared__ float sx[40];
  *(float4*)(su + lane*4) = *(const float4*)(u + (size_t)gid*DI + lane*4);
  __syncthreads();
  if (lane < 40) {
    const float* wr = Wx + ((size_t)dir*40 + lane)*DI;
    float acc = 0.f;
    #pragma unroll 8
    for (int k=0;k<256;k+=4) {
      float4 w4 = *(const float4*)(wr+k);
      acc += su[k]*w4.x + su[k+1]*w4.y + su[k+2]*w4.z + su[k+3]*w4.w;
    }
    sx[lane] = acc;
    if (lane >= 8 && lane < 24)      Bm[(size_t)gid*DS + lane-8]  = acc;
    else if (lane >= 24)             Cm[(size_t)gid*DS + lane-24] = acc;
  }
  __syncthreads();
  #pragma unroll
  for (int c=0;c<4;c++) {
    int d = lane + 64*c;
    const float* wd = Wdt + ((size_t)dir*DI + d)*DTR;
    float a = bdt[dir*DI + d];
    #pragma unroll
    for (int r=0;r<8;r++) a += sx[r]*wd[r];
    dt[(size_t)gid*DI + d] = softplus_(a);
  }
}

// ---------------- selective scan: 3-phase chunked ----------------
__global__ __launch_bounds__(256) void scan_p1(
    const float* __restrict__ dt, const float* __restrict__ u,
    const float* __restrict__ Bm, const float* __restrict__ Alog,
    float* __restrict__ cP, float* __restrict__ cH)
{
  int c = blockIdx.x, b = blockIdx.y, dir = blockIdx.z;
  int d = threadIdx.x;
  float A[DS], h[DS] = {}, P[DS];
  const float* al = Alog + ((size_t)dir*DI + d)*DS;
  #pragma unroll
  for (int s=0;s<DS;s++){ A[s] = -expf(al[s]); P[s] = 1.f; }
  int tlo = c*CHUNK, thi = min(tlo+CHUNK, LSEQ);
  int nt = thi - tlo;
  int t = dir ? thi-1 : tlo;
  int tstep = dir ? -1 : 1;
  for (int it=0; it<nt; it++, t+=tstep) {
    size_t g = (size_t)dir*TOK + (size_t)b*LSEQ + t;
    float dtv = dt[g*DI + d];
    float du  = dtv * u[g*DI + d];
    const float* Bp = Bm + g*DS;
    #pragma unroll
    for (int s=0;s<DS;s++) {
      float dA = expf(dtv*A[s]);
      h[s] = dA*h[s] + du*Bp[s];
      P[s] *= dA;
    }
  }
  size_t o = ((((size_t)dir*BATCH + b)*NCH + c)*DI + d)*DS;
  #pragma unroll
  for (int s=0;s<DS;s+=4) {
    *(float4*)(cP+o+s) = make_float4(P[s],P[s+1],P[s+2],P[s+3]);
    *(float4*)(cH+o+s) = make_float4(h[s],h[s+1],h[s+2],h[s+3]);
  }
}

__global__ __launch_bounds__(256) void scan_p2(
    const float* __restrict__ cP, float* __restrict__ cH)
{
  int gid = blockIdx.x*256 + threadIdx.x;   // (dir*8+b)*4096 + d*16+s
  int db = gid >> 12;
  int ds = gid & 4095;
  int dir = db >> 3;
  size_t base = (size_t)db*NCH*DI*DS + ds;
  float pref = 0.f;
  for (int i=0;i<NCH;i++) {
    int c = dir ? (NCH-1-i) : i;
    size_t a = base + (size_t)c*DI*DS;
    float Pv = cP[a], Hv = cH[a];
    cH[a] = pref;
    pref = Hv + Pv*pref;
  }
}

__global__ __launch_bounds__(256) void scan_p3(
    const float* __restrict__ dt, const float* __restrict__ u,
    const float* __restrict__ Bm, const float* __restrict__ Cm,
    const float* __restrict__ z, const float* __restrict__ Alog,
    const float* __restrict__ Dp, const float* __restrict__ cH,
    float* __restrict__ yg)
{
  int c = blockIdx.x, b = blockIdx.y, dir = blockIdx.z;
  int d = threadIdx.x;
  float A[DS], h[DS];
  const float* al = Alog + ((size_t)dir*DI + d)*DS;
  #pragma unroll
  for (int s=0;s<DS;s++) A[s] = -expf(al[s]);
  size_t o = ((((size_t)dir*BATCH + b)*NCH + c)*DI + d)*DS;
  #pragma unroll
  for (int s=0;s<DS;s+=4) {
    float4 v = *(const float4*)(cH+o+s);
    h[s]=v.x; h[s+1]=v.y; h[s+2]=v.z; h[s+3]=v.w;
  }
  float Dd = Dp[dir*DI + d];
  int tlo = c*CHUNK, thi = min(tlo+CHUNK, LSEQ);
  int nt = thi - tlo;
  int t = dir ? thi-1 : tlo;
  int tstep = dir ? -1 : 1;
  for (int it=0; it<nt; it++, t+=tstep) {
    size_t g = (size_t)dir*TOK + (size_t)b*LSEQ + t;
    float dtv = dt[g*DI + d];
    float uv  = u[g*DI + d];
    float du  = dtv * uv;
    const float* Bp = Bm + g*DS;
    const float* Cp = Cm + g*DS;
    float y = 0.f;
    #pragma unroll
    for (int s=0;s<DS;s++) {
      float dA = expf(dtv*A[s]);
      h[s] = dA*h[s] + du*Bp[s];
      y += h[s]*Cp[s];
    }
    float zv = z[g*DI + d];
    yg[g*DI + d] = (y + uv*Dd) * (zv * sigm_(zv));
  }
}

// ---------------- Wcomb[l][dir] = mergew_half @ Wout ----------------
__global__ __launch_bounds__(256) void make_wcomb(
    const float* __restrict__ mergew, const float* __restrict__ mWout,
    float* __restrict__ Wc)
{
  int m = blockIdx.x;          // 0..127
  int lm = blockIdx.y;         // l*2+dir
  int k = threadIdx.x;         // 0..255
  int l = lm >> 1, dir = lm & 1;
  __shared__ float sm[128];
  if (k < 128) sm[k] = mergew[((size_t)l*DM + m)*(2*DM) + dir*DM + k];
  __syncthreads();
  const float* wo = mWout + (size_t)lm*DM*DI;
  float acc = 0.f;
  #pragma unroll 4
  for (int j=0;j<128;j++) acc += sm[j]*wo[(size_t)j*DI + k];
  Wc[((size_t)lm*DM + m)*DI + k] = acc;
}

// ---------------- head: LN(cls) -> gelu linear -> linear ----------------
__global__ __launch_bounds__(64) void head_kernel(
    const float* __restrict__ x, const float* __restrict__ nfw, const float* __restrict__ nfb,
    const float* __restrict__ h1w, const float* __restrict__ h1b,
    const float* __restrict__ h2w, const float* __restrict__ h2b,
    float* __restrict__ out)
{
  int b = blockIdx.x, lane = threadIdx.x;
  __shared__ float sx[128];
  __shared__ float sh[32];
  const float* row = x + (size_t)b*LSEQ*DM;
  float2 v = *(const float2*)(row + lane*2);
  float s = v.x + v.y;
  #pragma unroll
  for (int o=32;o;o>>=1) s += __shfl_xor(s, o);
  float mean = s * (1.f/DM);
  float dx = v.x-mean, dy = v.y-mean;
  float q = dx*dx + dy*dy;
  #pragma unroll
  for (int o=32;o;o>>=1) q += __shfl_xor(q, o);
  float inv = 1.f/sqrtf(q*(1.f/DM) + 1e-5f);
  sx[lane*2]   = dx*inv*nfw[lane*2]   + nfb[lane*2];
  sx[lane*2+1] = dy*inv*nfw[lane*2+1] + nfb[lane*2+1];
  __syncthreads();
  if (lane < 32) {
    const float* wr = h1w + (size_t)lane*DM;
    float a = h1b[lane];
    #pragma unroll 4
    for (int k=0;k<128;k++) a += sx[k]*wr[k];
    sh[lane] = gelu_(a);
  }
  __syncthreads();
  if (lane == 0) {
    float a = h2b[0];
    #pragma unroll
    for (int j=0;j<32;j++) a += sh[j]*h2w[j];
    out[b] = a;
  }
}

// ---------------- host ----------------
extern "C" void kernel_launch(void* const* d_in, const int* in_sizes, int n_in,
                              void* d_out, int out_size, void* d_ws, size_t ws_size,
                              hipStream_t stream)
{
  (void)in_sizes; (void)n_in; (void)out_size; (void)ws_size;
  const float* img    = (const float*)d_in[0];
  const float* patchw = (const float*)d_in[1];
  const float* patchb = (const float*)d_in[2];
  const float* cls    = (const float*)d_in[3];
  const float* pos    = (const float*)d_in[4];
  const float* n1w    = (const float*)d_in[5];
  const float* n1b    = (const float*)d_in[6];
  const float* mWin   = (const float*)d_in[7];
  const float* mConvw = (const float*)d_in[8];
  const float* mConvb = (const float*)d_in[9];
  const float* mWx    = (const float*)d_in[10];
  const float* mWdt   = (const float*)d_in[11];
  const float* mbdt   = (const float*)d_in[12];
  const float* mAlog  = (const float*)d_in[13];
  const float* mD     = (const float*)d_in[14];
  const float* mWout  = (const float*)d_in[15];
  const float* mergew = (const float*)d_in[16];
  const float* mergeb = (const float*)d_in[17];
  const float* n2w    = (const float*)d_in[18];
  const float* n2b    = (const float*)d_in[19];
  const float* f1w    = (const float*)d_in[20];
  const float* f1b    = (const float*)d_in[21];
  const float* f2w    = (const float*)d_in[22];
  const float* f2b    = (const float*)d_in[23];
  const float* nfw    = (const float*)d_in[24];
  const float* nfb    = (const float*)d_in[25];
  const float* h1w    = (const float*)d_in[26];
  const float* h1b    = (const float*)d_in[27];
  const float* h2w    = (const float*)d_in[28];
  const float* h2b    = (const float*)d_in[29];
  float* out = (float*)d_out;

  float* ws = (float*)d_ws;
  size_t off = 0;
  auto alloc = [&](size_t n){ float* p = ws + off; off += n; return p; };
  float* x    = alloc((size_t)TOK*DM);
  float* xn   = alloc((size_t)TOK*DM);
  float* upre = alloc((size_t)2*TOK*DI);   // reused as yg after conv
  float* zb   = alloc((size_t)2*TOK*DI);
  float* ub   = alloc((size_t)2*TOK*DI);
  float* dtb  = alloc((size_t)2*TOK*DI);   // reused as hdd (TOK*512) in FFN
  float* Bmb  = alloc((size_t)2*TOK*DS);
  float* Cmb  = alloc((size_t)2*TOK*DS);
  float* cP   = alloc((size_t)2*BATCH*NCH*DI*DS);
  float* cH   = alloc((size_t)2*BATCH*NCH*DI*DS);
  float* Wc   = alloc((size_t)12*DM*DI);
  float* yg   = upre;
  float* hdd  = dtb;

  const int MT = (TOK + 63) / 64;   // 129

  make_wcomb<<<dim3(128,12), 256, 0, stream>>>(mergew, mWout, Wc);
  patch_embed<<<TOK, 128, 0, stream>>>(img, patchw, patchb, cls, pos, x);

  for (int l = 0; l < 6; l++) {
    ln128<<<TOK, 64, 0, stream>>>(x, xn, n1w + l*DM, n1b + l*DM);
    // in_proj for both directions: N=1024, split-store to upre/z
    sgemm<3><<<dim3(MT,16), 256, 0, stream>>>(
        xn, nullptr, mWin + (size_t)l*2*512*DM, nullptr,
        nullptr, upre, zb, TOK, 1024, DM, DM, 0);
    conv_silu<<<2*TOK, DI, 0, stream>>>(
        upre, mConvw + (size_t)l*2*DI*4, mConvb + (size_t)l*2*DI, ub);
    xproj<<<2*TOK, 64, 0, stream>>>(
        ub, mWx + (size_t)l*2*40*DI, mWdt + (size_t)l*2*DI*DTR,
        mbdt + (size_t)l*2*DI, dtb, Bmb, Cmb);
    scan_p1<<<dim3(NCH,BATCH,2), DI, 0, stream>>>(
        dtb, ub, Bmb, mAlog + (size_t)l*2*DI*DS, cP, cH);
    scan_p2<<<(2*BATCH*DI*DS)/256, 256, 0, stream>>>(cP, cH);
    scan_p3<<<dim3(NCH,BATCH,2), DI, 0, stream>>>(
        dtb, ub, Bmb, Cmb, zb, mAlog + (size_t)l*2*DI*DS,
        mD + (size_t)l*2*DI, cH, yg);
    // fused out_proj + merge (+bias, residual add): K=512 dual-A dual-W
    sgemm<2><<<dim3(MT,2), 256, 0, stream>>>(
        yg, yg + (size_t)TOK*DI,
        Wc + (size_t)(l*2)*DM*DI, Wc + (size_t)(l*2+1)*DM*DI,
        mergeb + l*DM, x, nullptr, TOK, DM, 2*DI, DI, DM);
    // FFN
    ln128<<<TOK, 64, 0, stream>>>(x, xn, n2w + l*DM, n2b + l*DM);
    sgemm<1><<<dim3(MT,8), 256, 0, stream>>>(
        xn, nullptr, f1w + (size_t)l*512*DM, nullptr,
        f1b + l*512, hdd, nullptr, TOK, 512, DM, DM, 512);
    sgemm<2><<<dim3(MT,2), 256, 0, stream>>>(
        hdd, nullptr, f2w + (size_t)l*DM*512, nullptr,
        f2b + l*DM, x, nullptr, TOK, DM, 512, 512, DM);
  }

  head_kernel<<<BATCH, 64, 0, stream>>>(x, nfw, nfb, h1w, h1b, h2w, h2b, out);
}